// Round 6
// baseline (594.219 us; speedup 1.0000x reference)
//
#include <hip/hip_runtime.h>
#include <hip/hip_bf16.h>
#include <cstdint>

// Problem constants
#define BSZ   4
#define TLEN  4096
#define DM    1024
#define NS    256
#define DFF   2736
#define DFFP  2816        // padded to multiple of 128
#define NPK   5632        // interleaved w1/w3 rows (2*DFFP)
#define NCHUNK 64
#define CLEN   64         // TLEN / NCHUNK

typedef __attribute__((ext_vector_type(8))) short bf16x8;
typedef __attribute__((ext_vector_type(4))) float f32x4;

__device__ __forceinline__ float bf2f(ushort u) {
  union { unsigned int i; float f; } v; v.i = ((unsigned int)u) << 16; return v.f;
}
__device__ __forceinline__ ushort f2bf(float f) {
  union { float f; unsigned int i; } v; v.f = f;
  unsigned int r = v.i + 0x7FFFu + ((v.i >> 16) & 1u);
  return (ushort)(r >> 16);
}
__device__ __forceinline__ void gload16(const ushort* g, ushort* l) {
  __builtin_amdgcn_global_load_lds((const __attribute__((address_space(1))) void*)g,
                                   (__attribute__((address_space(3))) void*)l, 16, 0, 0);
}
#define BAR() asm volatile("s_barrier" ::: "memory")

// ---------------- weight convert + pad to bf16 ----------------
__global__ void convert_pad(const float* __restrict__ src, ushort* __restrict__ dst,
                            int srcR, int srcC, int dstR, int dstC) {
  long total = (long)dstR * dstC / 4;
  for (long q = (long)blockIdx.x * blockDim.x + threadIdx.x; q < total;
       q += (long)gridDim.x * blockDim.x) {
    long e = q * 4;
    int r = (int)(e / dstC);
    int c = (int)(e % dstC);
    ushort4 o;
    float v0 = (r < srcR && c + 0 < srcC) ? src[(long)r * srcC + c + 0] : 0.f;
    float v1 = (r < srcR && c + 1 < srcC) ? src[(long)r * srcC + c + 1] : 0.f;
    float v2 = (r < srcR && c + 2 < srcC) ? src[(long)r * srcC + c + 2] : 0.f;
    float v3 = (r < srcR && c + 3 < srcC) ? src[(long)r * srcC + c + 3] : 0.f;
    o.x = f2bf(v0); o.y = f2bf(v1); o.z = f2bf(v2); o.w = f2bf(v3);
    *(ushort4*)(dst + e) = o;
  }
}

// ---------------- pack w1/w3 interleaved (16-row groups), padded ----------------
__global__ void pack_w13(const float* __restrict__ w1, const float* __restrict__ w3,
                         ushort* __restrict__ wp) {
  long total = (long)NPK * DM / 4;
  for (long q = (long)blockIdx.x * blockDim.x + threadIdx.x; q < total;
       q += (long)gridDim.x * blockDim.x) {
    long e = q * 4;
    int r = (int)(e >> 10);
    int c = (int)(e & 1023);
    int f = ((r >> 5) << 4) + (r & 15);
    const float* src = ((r >> 4) & 1) ? w3 : w1;
    ushort4 o;
    if (f < DFF) {
      const float4 v = *(const float4*)(src + (long)f * DM + c);
      o.x = f2bf(v.x); o.y = f2bf(v.y); o.z = f2bf(v.z); o.w = f2bf(v.w);
    } else {
      o.x = o.y = o.z = o.w = 0;
    }
    *(ushort4*)(wp + e) = o;
  }
}

// ---------------- RMSNorm (f32 in -> bf16 out) ----------------
__global__ __launch_bounds__(256) void rmsnorm_bf16(const float* __restrict__ x,
                                                    const float* __restrict__ w,
                                                    ushort* __restrict__ out) {
  long row = blockIdx.x;
  int tid = threadIdx.x;
  const float4* xr = (const float4*)(x + row * DM);
  float4 v = xr[tid];
  float ss = v.x * v.x + v.y * v.y + v.z * v.z + v.w * v.w;
#pragma unroll
  for (int m = 32; m >= 1; m >>= 1) ss += __shfl_xor(ss, m);
  __shared__ float red[4];
  if ((tid & 63) == 0) red[tid >> 6] = ss;
  __syncthreads();
  float tot = red[0] + red[1] + red[2] + red[3];
  float inv = rsqrtf(tot * (1.0f / DM) + 1e-6f);
  float4 wv = ((const float4*)w)[tid];
  ushort4 o;
  o.x = f2bf(v.x * inv * wv.x);
  o.y = f2bf(v.y * inv * wv.y);
  o.z = f2bf(v.z * inv * wv.z);
  o.w = f2bf(v.w * inv * wv.w);
  ((ushort4*)(out + row * DM))[tid] = o;
}

// ---------------- scan phase A: local per-chunk scan (in place) ----------------
__global__ __launch_bounds__(256) void scan_local(float* __restrict__ Bu,
                                                  float* __restrict__ E,
                                                  const float* __restrict__ loglam) {
  int bc = blockIdx.x;
  int b = bc / NCHUNK, c = bc % NCHUNK;
  int n = threadIdx.x;
  float lam = 1.f / (1.f + __expf(-loglam[n]));
  float h = 0.f;
  long base = ((long)b * TLEN + (long)c * CLEN) * NS + n;
#pragma unroll 4
  for (int t = 0; t < CLEN; ++t) {
    long idx = base + (long)t * NS;
    h = lam * h + Bu[idx];
    Bu[idx] = h;
  }
  E[((long)b * NCHUNK + c) * NS + n] = h;
}

// ---------------- scan phase B: chunk-carry combine ----------------
__global__ __launch_bounds__(1024) void scan_carry(const float* __restrict__ E,
                                                   float* __restrict__ C,
                                                   const float* __restrict__ loglam) {
  int tid = threadIdx.x;
  int b = tid >> 8, n = tid & 255;
  float lam = 1.f / (1.f + __expf(-loglam[n]));
  float lamL = lam;
#pragma unroll
  for (int i = 0; i < 6; ++i) lamL *= lamL;   // lam^64
  float carry = 0.f;
  for (int c = 0; c < NCHUNK; ++c) {
    long idx = ((long)b * NCHUNK + c) * NS + n;
    C[idx] = carry;
    carry = lamL * carry + E[idx];
  }
}

// ---------------- scan phase C: add carry, emit bf16 hs ----------------
__global__ __launch_bounds__(256) void scan_fix(const float* __restrict__ local,
                                                const float* __restrict__ Carry,
                                                const float* __restrict__ loglam,
                                                ushort* __restrict__ hsb) {
  int bc = blockIdx.x;
  int b = bc / NCHUNK, c = bc % NCHUNK;
  int n = threadIdx.x;
  float lam = 1.f / (1.f + __expf(-loglam[n]));
  float p = Carry[((long)b * NCHUNK + c) * NS + n];
  long base = ((long)b * TLEN + (long)c * CLEN) * NS + n;
#pragma unroll 4
  for (int t = 0; t < CLEN; ++t) {
    p *= lam;
    long idx = base + (long)t * NS;
    hsb[idx] = f2bf(local[idx] + p);
  }
}

// ---------------- small bf16 NT GEMM, 128x128x32 (m97 structure) ----------------
// EPI: 0 = store f32 ; 1 = out = acc + x + Dskip*u (residual-1, N==DM)
template <int EPI>
__global__ __launch_bounds__(256, 2) void gemm_bt(
    const ushort* __restrict__ A, const ushort* __restrict__ B0,
    float* __restrict__ outF,
    const float* __restrict__ xin, const float* __restrict__ dskip,
    const ushort* __restrict__ uin, int M, int N, int K) {
  __shared__ ushort sA[128 * 32];
  __shared__ ushort sB[128 * 32];

  int tid = threadIdx.x;
  int lane = tid & 63;
  int wid = tid >> 6;
  int nbx = N >> 7;
  int by = blockIdx.x / nbx;
  int bx = blockIdx.x - by * nbx;
  long brow = (long)by << 7;
  long bcol = (long)bx << 7;

  int srow = tid >> 2;
  int scol = (tid & 3) << 3;
  const ushort* gA = A + (brow + srow) * (long)K + scol;
  const ushort* gB = B0 + (bcol + srow) * (long)K + scol;
  ushort* lA = sA + (wid << 9);
  ushort* lB = sB + (wid << 9);

  int wr = wid >> 1, wc = wid & 1;
  int fr = lane & 15;
  int fk = (lane >> 4) << 3;

  f32x4 acc0[4][4];
#pragma unroll
  for (int i = 0; i < 4; ++i)
#pragma unroll
    for (int j = 0; j < 4; ++j) acc0[i][j] = (f32x4)0.f;

  long rowq = 64 * (long)K;
  for (int kt = 0; kt < K; kt += 32) {
    __syncthreads();
    gload16(gA + kt, lA);
    gload16(gA + kt + rowq, lA + 2048);
    gload16(gB + kt, lB);
    gload16(gB + kt + rowq, lB + 2048);
    __syncthreads();

    bf16x8 a[4], b[4];
#pragma unroll
    for (int i = 0; i < 4; ++i)
      a[i] = *(const bf16x8*)(sA + ((wr * 64 + i * 16 + fr) * 32 + fk));
#pragma unroll
    for (int j = 0; j < 4; ++j)
      b[j] = *(const bf16x8*)(sB + ((wc * 64 + j * 16 + fr) * 32 + fk));
#pragma unroll
    for (int i = 0; i < 4; ++i)
#pragma unroll
      for (int j = 0; j < 4; ++j)
        acc0[i][j] = __builtin_amdgcn_mfma_f32_16x16x32_bf16(a[i], b[j], acc0[i][j], 0, 0, 0);
  }

#pragma unroll
  for (int i = 0; i < 4; ++i) {
    int rowb = wr * 64 + i * 16 + ((lane >> 4) << 2);
#pragma unroll
    for (int j = 0; j < 4; ++j) {
      long gcol = bcol + wc * 64 + j * 16 + fr;
#pragma unroll
      for (int r = 0; r < 4; ++r) {
        long grow = brow + rowb + r;
        long idx = grow * N + gcol;
        float v = acc0[i][j][r];
        if constexpr (EPI == 0) {
          outF[idx] = v;
        } else {
          outF[idx] = v + xin[idx] + dskip[gcol] * bf2f(uin[idx]);
        }
      }
    }
  }
}

// ---------------- big bf16 NT GEMM, 256x256x64, 8-phase schedule (T2+T3+T4+T5) --
// A [16384,K] bf16; B [N,K] bf16. 512 thr = 8 waves (2M x 4N), wave = 128x64.
// LDS: 2 dbufs x (A 256x64 + B 256x64) = 131072 B. dbuf d holds K-tile 2u+d.
// Stage unit = "half": A_X = tile rows with bit6=0 (read only at mh=0 phases),
// A_Y = bit6=1 (mh=1); B_X = bit5=0 (nh=0), B_Y = bit5=1 (nh=1). 1 half = 2 gloads.
// Iteration u = 8 phases over quadrants (dbuf, mh, nh):
//  P0 (d0,0,0): read a(mh0)+b(nh0)[12]; stage d1.A_Y (tile 2u+1)  [AY last read P7]
//  P1 (d0,0,1): read b(nh1)[4];         stage d0.A_X (tile 2u+2)  [AX last read P0]
//  P2 (d0,1,0): read a(mh1)[8];         stage d0.B_X              [BX last read P0]
//  P3 (d0,1,1): no reads;               stage d0.B_Y              [BY last read P1]
//               then vmcnt(6) BEFORE end-barrier (drains prev P5,P6,P7 + this P0
//               = dbuf1's 4 halves; each wave drains own loads pre-barrier ->
//               cross-wave visible after barrier). Last iter: vmcnt(0).
//  P4 (d1,0,0): read a+b[12];           stage d0.A_Y              [AY last read P2]
//  P5 (d1,0,1): read b[4];              stage d1.A_X (tile 2u+3)  [AX last read P4]
//  P6 (d1,1,0): read a[8];              stage d1.B_X              [BX last read P4]
//  P7 (d1,1,1): no reads;               stage d1.B_Y              [BY last read P5]
//               then vmcnt(6) before end-barrier (drains P1..P4 = dbuf0 t+2 tile).
// Each phase: [reads; stage; BAR; (compiler lgkm waits); setprio(1); 16 MFMA;
// setprio(0); (vmcnt); BAR]. Every staged region's last LDS-read is >=1 barrier
// before its restage. Swizzle: 16B slot cs at cs^(row&7), 0 bank conflicts.
template <bool DUAL>
__global__ __launch_bounds__(512, 2) void big_gemm(
    const ushort* __restrict__ A, const ushort* __restrict__ Bm,
    float* __restrict__ outF, ushort* __restrict__ outU) {
  constexpr int K = DUAL ? DM : DFFP;
  constexpr int NT = K / 64;
  constexpr int NI = NT / 2;
  extern __shared__ __align__(16) char smem_raw[];
  ushort* lds = (ushort*)smem_raw;

  int tid = threadIdx.x;
  int lane = tid & 63;
  int wid = tid >> 6;

  // supertile mapping: chunk (XCD) = bid&7 owns rows [chunk*8, chunk*8+8)
  int bid = blockIdx.x;
  int chunk = bid & 7;
  int w = bid >> 3;
  int rt = chunk * 8 + (w & 7);
  int ct = w >> 3;
  long brow = (long)rt << 8;
  long bcol = (long)ct << 8;

  // staging source offsets (pre-swizzled) + wave-uniform LDS dst offsets
  uint aSrc[2], bSrc[2];
  int aDst[2], bDst[2];
#pragma unroll
  for (int p = 0; p < 2; ++p) {
    int s = p * 512 + tid;
    int lr = s >> 3;                       // 0..127 local row within half
    int cs = s & 7;                        // 16B col slot
    int csx = cs ^ (lr & 7);
    int rA = ((lr >> 6) << 7) | (lr & 63); // bit6 -> bit7 (A_X rows)
    int rB = ((lr >> 5) << 6) | (lr & 31); // bit5 -> bit6 (B_X rows)
    aSrc[p] = (uint)((brow + rA) * (long)K + csx * 8);
    bSrc[p] = (uint)((bcol + rB) * (long)K + csx * 8);
    aDst[p] = (rA & ~7) * 64;              // wave-uniform (HW adds lane*16B)
    bDst[p] = 16384 + (rB & ~7) * 64;
  }

  int wm = wid >> 2, wn = wid & 3;         // 2 x 4 waves, wave tile 128 x 64
  int fr = lane & 15, fq = lane >> 4;
  int sl[2];
  sl[0] = ((0 * 4 + fq) ^ (fr & 7)) << 3;
  sl[1] = ((1 * 4 + fq) ^ (fr & 7)) << 3;

  f32x4 acc[8][4];
#pragma unroll
  for (int m = 0; m < 8; ++m)
#pragma unroll
    for (int n = 0; n < 4; ++n) acc[m][n] = (f32x4)0.f;

  bf16x8 afr[4][2];        // current a-half fragments
  bf16x8 bfr[2][2][2];     // [nh][frag][kk]

  auto STAGE_A = [&](long gk, int d, int half) {
    const ushort* Ag = A + gk * 64 + (long)half * (64L * K);
    ushort* lb = lds + d * 32768 + half * 4096;
#pragma unroll
    for (int p = 0; p < 2; ++p) gload16(Ag + aSrc[p], lb + aDst[p]);
  };
  auto STAGE_B = [&](long gk, int d, int half) {
    const ushort* Bg = Bm + gk * 64 + (long)half * (32L * K);
    ushort* lb = lds + d * 32768 + half * 2048;
#pragma unroll
    for (int p = 0; p < 2; ++p) gload16(Bg + bSrc[p], lb + bDst[p]);
  };
  auto LDA = [&](const ushort* lb, int mh) {
#pragma unroll
    for (int i = 0; i < 4; ++i) {
      int row = wm * 128 + (mh * 4 + i) * 16 + fr;
#pragma unroll
      for (int kk = 0; kk < 2; ++kk)
        afr[i][kk] = *(const bf16x8*)(lb + row * 64 + sl[kk]);
    }
  };
  auto LDB = [&](const ushort* lb, int nh) {
#pragma unroll
    for (int j = 0; j < 2; ++j) {
      int row = wn * 64 + (nh * 2 + j) * 16 + fr;
#pragma unroll
      for (int kk = 0; kk < 2; ++kk)
        bfr[nh][j][kk] = *(const bf16x8*)(lb + 16384 + row * 64 + sl[kk]);
    }
  };
  auto MF = [&](int mh, int nh) {
    __builtin_amdgcn_s_setprio(1);
#pragma unroll
    for (int kk = 0; kk < 2; ++kk)
#pragma unroll
      for (int i = 0; i < 4; ++i)
#pragma unroll
        for (int j = 0; j < 2; ++j)
          acc[mh * 4 + i][nh * 2 + j] = __builtin_amdgcn_mfma_f32_16x16x32_bf16(
              afr[i][kk], bfr[nh][j][kk], acc[mh * 4 + i][nh * 2 + j], 0, 0, 0);
    __builtin_amdgcn_s_setprio(0);
  };

  // prologue: T0 {AX,BX,BY,AY} -> dbuf0; T1 {AX,BX,BY} -> dbuf1 (14 loads)
  STAGE_A(0, 0, 0); STAGE_B(0, 0, 0); STAGE_B(0, 0, 1); STAGE_A(0, 0, 1);
  STAGE_A(1, 1, 0); STAGE_B(1, 1, 0); STAGE_B(1, 1, 1);
  asm volatile("s_waitcnt vmcnt(6)" ::: "memory");   // dbuf0 landed; T1 flying
  BAR();

  const ushort* lb0 = lds;
  const ushort* lb1 = lds + 32768;
#pragma unroll 1
  for (int u = 0; u < NI; ++u) {
    long t1 = 2L * u + 1, t2 = 2L * u + 2, t3 = 2L * u + 3;
    bool nl = (u + 1 < NI);
    // P0
    LDA(lb0, 0); LDB(lb0, 0);
    STAGE_A(t1, 1, 1);
    BAR(); MF(0, 0); BAR();
    // P1
    LDB(lb0, 1);
    if (nl) STAGE_A(t2, 0, 0);
    BAR(); MF(0, 1); BAR();
    // P2
    LDA(lb0, 1);
    if (nl) STAGE_B(t2, 0, 0);
    BAR(); MF(1, 0); BAR();
    // P3
    if (nl) STAGE_B(t2, 0, 1);
    BAR(); MF(1, 1);
    if (nl) asm volatile("s_waitcnt vmcnt(6)" ::: "memory");
    else    asm volatile("s_waitcnt vmcnt(0)" ::: "memory");
    BAR();
    // P4
    LDA(lb1, 0); LDB(lb1, 0);
    if (nl) STAGE_A(t2, 0, 1);
    BAR(); MF(0, 0); BAR();
    // P5
    LDB(lb1, 1);
    if (nl) STAGE_A(t3, 1, 0);
    BAR(); MF(0, 1); BAR();
    // P6
    LDA(lb1, 1);
    if (nl) STAGE_B(t3, 1, 0);
    BAR(); MF(1, 0); BAR();
    // P7
    if (nl) STAGE_B(t3, 1, 1);
    BAR(); MF(1, 1);
    if (nl) asm volatile("s_waitcnt vmcnt(6)" ::: "memory");
    BAR();
  }

  // epilogue (C/D: col = lane&15, row = (lane>>4)*4 + reg)
#pragma unroll
  for (int m = 0; m < 8; ++m) {
    int rowb = wm * 128 + m * 16 + fq * 4;
    if constexpr (DUAL) {
#pragma unroll
      for (int jp = 0; jp < 2; ++jp) {
        long fcol = (bcol >> 1) + wn * 32 + jp * 16 + fr;
#pragma unroll
        for (int r = 0; r < 4; ++r) {
          long grow = brow + rowb + r;
          float gt = acc[m][2 * jp][r];
          float vl = acc[m][2 * jp + 1][r];
          float s = gt / (1.f + __expf(-gt));
          outU[grow * DFFP + fcol] = f2bf(s * vl);
        }
      }
    } else {
#pragma unroll
      for (int n = 0; n < 4; ++n) {
        long gcol = bcol + wn * 64 + n * 16 + fr;
#pragma unroll
        for (int r = 0; r < 4; ++r) {
          long grow = brow + rowb + r;
          outF[grow * DM + gcol] += acc[m][n][r];
        }
      }
    }
  }
}

// ---------------- launch ----------------
extern "C" void kernel_launch(void* const* d_in, const int* in_sizes, int n_in,
                              void* d_out, int out_size, void* d_ws, size_t ws_size,
                              hipStream_t stream) {
  const float* x      = (const float*)d_in[0];
  const float* loglam = (const float*)d_in[1];
  const float* B_w    = (const float*)d_in[2];
  const float* C_w    = (const float*)d_in[3];
  const float* D_skip = (const float*)d_in[4];
  const float* ssm_w  = (const float*)d_in[5];
  const float* ffn_w  = (const float*)d_in[6];
  const float* w1     = (const float*)d_in[7];
  const float* w2     = (const float*)d_in[8];
  const float* w3     = (const float*)d_in[9];
  float* out = (float*)d_out;

  char* ws = (char*)d_ws;
  ushort* u_bf  = (ushort*)(ws + 0);           // 33554432
  float*  Bu    = (float*) (ws + 33554432);    // 16777216
  ushort* hs_bf = (ushort*)(ws + 50331648);    // 8388608
  float*  E     = (float*) (ws + 58720256);    // 262144
  float*  Carry = (float*) (ws + 58982400);    // 262144
  ushort* wB    = (ushort*)(ws + 59244544);    // 524288
  ushort* wC    = (ushort*)(ws + 59768832);    // 524288
  ushort* Wp    = (ushort*)(ws + 60293120);    // 11534336 (interleaved w1/w3)
  ushort* w2p   = (ushort*)(ws + 71827456);    // 5767168
  ushort* gv    = (ushort*)(ws + 77594624);    // 92274688 -> total 169869312

  constexpr int BIG_LDS = 131072;
  (void)hipFuncSetAttribute((const void*)&big_gemm<true>,
                            hipFuncAttributeMaxDynamicSharedMemorySize, BIG_LDS);
  (void)hipFuncSetAttribute((const void*)&big_gemm<false>,
                            hipFuncAttributeMaxDynamicSharedMemorySize, BIG_LDS);

  auto cvb = [](long elems) {
    long q = elems / 4;
    long b = (q + 255) / 256;
    return (int)(b > 4096 ? 4096 : b);
  };

  // weight conversion
  convert_pad<<<cvb(256L * 1024), 256, 0, stream>>>(B_w, wB, 256, 1024, 256, 1024);
  convert_pad<<<cvb(1024L * 256), 256, 0, stream>>>(C_w, wC, 1024, 256, 1024, 256);
  pack_w13<<<2048, 256, 0, stream>>>(w1, w3, Wp);
  convert_pad<<<cvb(1024L * DFFP), 256, 0, stream>>>(w2, w2p, 1024, DFF, 1024, DFFP);

  // SSM branch
  rmsnorm_bf16<<<BSZ * TLEN, 256, 0, stream>>>(x, ssm_w, u_bf);
  gemm_bt<0><<<(16384 / 128) * (NS / 128), 256, 0, stream>>>(
      u_bf, wB, Bu, nullptr, nullptr, nullptr, 16384, NS, DM);
  scan_local<<<BSZ * NCHUNK, 256, 0, stream>>>(Bu, E, loglam);
  scan_carry<<<1, 1024, 0, stream>>>(E, Carry, loglam);
  scan_fix<<<BSZ * NCHUNK, 256, 0, stream>>>(Bu, Carry, loglam, hs_bf);
  gemm_bt<1><<<(16384 / 128) * (DM / 128), 256, 0, stream>>>(
      hs_bf, wC, out, x, D_skip, u_bf, 16384, DM, NS);

  // FFN branch
  rmsnorm_bf16<<<BSZ * TLEN, 256, 0, stream>>>(out, ffn_w, u_bf);  // z reuses u buffer
  big_gemm<true><<<8 * 8 * (NPK / 256), 512, BIG_LDS, stream>>>(u_bf, Wp, nullptr, gv);
  big_gemm<false><<<8 * 8 * (DM / 256), 512, BIG_LDS, stream>>>(gv, w2p, out, nullptr);
}